// Round 14
// baseline (211.371 us; speedup 1.0000x reference)
//
#include <hip/hip_runtime.h>
#include <hip/hip_bf16.h>

#define BB 16
#define NI 2048
#define NA 2048
#define DD 256
#define KVB 32
#define NT (NA / KVB)    // 64

typedef _Float16 half8 __attribute__((ext_vector_type(8)));
typedef __attribute__((ext_vector_type(4))) float f32x4;
typedef __attribute__((ext_vector_type(4))) unsigned int uint4v;

typedef const unsigned int CGU __attribute__((address_space(1)));
typedef unsigned int LU __attribute__((address_space(3)));

static __device__ __forceinline__ unsigned short f2h(float f) {
  union { _Float16 h; unsigned short u; } x; x.h = (_Float16)f; return x.u;
}
static __device__ __forceinline__ float h2f(unsigned short u) {
  union { _Float16 h; unsigned short u; } x; x.u = u; return (float)x.h;
}
static __device__ __forceinline__ unsigned int pk2(float a, float b) {
  return __builtin_bit_cast(unsigned int, __builtin_amdgcn_cvt_pkrtz(a, b));
}
static __device__ __forceinline__ unsigned int f2u(float f) {
  return __builtin_bit_cast(unsigned int, f);
}
static __device__ __forceinline__ float u2f(unsigned int u) {
  return __builtin_bit_cast(float, u);
}
// async global->LDS, 16B/lane; dst is wave-uniform base (HW adds lane*16)
static __device__ __forceinline__ void gload16(const unsigned short* g, unsigned short* l) {
  __builtin_amdgcn_global_load_lds((CGU*)g, (LU*)l, 16, 0, 0);
}

// ---------------- prep (+fused tw): attendee -> kfrag + vfrag; W -> wth/wtl ----------------
// kfrag[b][kt][c(8)][jt(2)][lane(64)][e(8)]: lane=quad*16+l16 holds K[jb+jt*16+l16][c*32+quad*8+e]
// vfrag[b][kt][h(2)][dt(8)][lane(64)][e(8)]: lane holds V^T[h*128+dt*16+l16][jb + pi(quad,e)]
//   pi(quad,e) = (e>>2)*16 + 4*quad + (e&3)  — matches P's natural post-QK^T layout.
__global__ void prep_kernel(const float* __restrict__ a,
                            unsigned short* __restrict__ kfrag,
                            unsigned short* __restrict__ vfrag,
                            const float* __restrict__ w,
                            unsigned short* __restrict__ wth,
                            unsigned short* __restrict__ wtl) {
  __shared__ float t[64][65];
  int bx = blockIdx.x;
  int tid = threadIdx.x;
  int rr = tid >> 4, c4 = tid & 15;

  if (bx >= 2048) {
    // ---- tw: W -> W^T hi/lo fp16, row-XOR-swizzled [e][d] ----
    int r = bx - 2048;
    int dt = r >> 2, et = r & 3;
    int d0 = dt * 64, e0 = et * 64;
    int cc = c4 * 4;
#pragma unroll
    for (int k = 0; k < 4; ++k) {
      int row = rr + k * 16;   // d index
      float4 v = *(const float4*)(w + (size_t)(d0 + row) * DD + e0 + cc);
      t[row][cc + 0] = v.x; t[row][cc + 1] = v.y; t[row][cc + 2] = v.z; t[row][cc + 3] = v.w;
    }
    __syncthreads();
#pragma unroll
    for (int k = 0; k < 4; ++k) {
      int e = rr + k * 16;
      int eg = e0 + e;
      ushort4 h, l;
      float v0 = t[cc + 0][e]; h.x = f2h(v0); l.x = f2h(v0 - h2f(h.x));
      float v1 = t[cc + 1][e]; h.y = f2h(v1); l.y = f2h(v1 - h2f(h.y));
      float v2 = t[cc + 2][e]; h.z = f2h(v2); l.z = f2h(v2 - h2f(h.z));
      float v3 = t[cc + 3][e]; h.w = f2h(v3); l.w = f2h(v3 - h2f(h.w));
      int dd = d0 + cc;
      int u = dd >> 3, sub = dd & 7;
      size_t off = (size_t)eg * DD + ((u ^ (eg & 7)) * 8) + sub;
      *(ushort4*)(wth + off) = h;
      *(ushort4*)(wtl + off) = l;
    }
    return;
  }

  int b = bx >> 7;
  int r = bx & 127;
  int jt_t = r >> 2, dt_t = r & 3;
  int j0 = jt_t * 64, d0 = dt_t * 64;
#pragma unroll
  for (int k = 0; k < 4; ++k) {
    int row = rr + k * 16;
    int j = j0 + row;
    int d = d0 + c4 * 4;
    float4 v = *(const float4*)(a + ((size_t)b * NA + j) * DD + d);
    ushort4 hh;
    hh.x = f2h(v.x); hh.y = f2h(v.y); hh.z = f2h(v.z); hh.w = f2h(v.w);
    int kt = j >> 5, jtf = (j >> 4) & 1, l16k = j & 15;
    int c = d >> 5, quad = (d >> 3) & 3, e = d & 7;
    *(ushort4*)(kfrag + ((size_t)b * NT + kt) * 8192 + c * 1024 + jtf * 512 +
                (quad * 16 + l16k) * 8 + e) = hh;
    t[row][c4 * 4 + 0] = v.x; t[row][c4 * 4 + 1] = v.y;
    t[row][c4 * 4 + 2] = v.z; t[row][c4 * 4 + 3] = v.w;
  }
  __syncthreads();
#pragma unroll
  for (int k = 0; k < 4; ++k) {
    int dl = rr + k * 16;
    int d = d0 + dl;
    int j = j0 + c4 * 4;              // 4 consecutive j
    ushort4 o;
    o.x = f2h(t[c4 * 4 + 0][dl]); o.y = f2h(t[c4 * 4 + 1][dl]);
    o.z = f2h(t[c4 * 4 + 2][dl]); o.w = f2h(t[c4 * 4 + 3][dl]);
    int kt = j >> 5;
    int quad = c4 & 3;                // pi-inverse: j=j0+4*c4+i -> quad=c4&3
    int jt = (c4 >> 2) & 1;           // e = jt*4 + i
    int hh_ = (d >> 7) & 1, dtl = (d >> 4) & 7, l16v = d & 15;
    *(ushort4*)(vfrag + ((size_t)b * NT + kt) * 8192 + hh_ * 4096 + dtl * 512 +
                (quad * 16 + l16v) * 8 + jt * 4) = o;
  }
}

// ---------------- Q = (x @ W) * log2(e)  (2-term fp16 MFMA), writes qf fp16 row-major ----------------
__global__ __launch_bounds__(256, 2) void qgemm_kernel(
    const float* __restrict__ x, const unsigned short* __restrict__ wth,
    const unsigned short* __restrict__ wtl, unsigned short* __restrict__ qf) {
  __shared__ unsigned short wb[2][64 * 256];   // 64 KB
  const int tid = threadIdx.x;
  const int lane = tid & 63;
  const int wv = tid >> 6;
  const int quad = lane >> 4;
  const int l16 = lane & 15;
  const int m0 = blockIdx.x * 64;

  half8 xf[8];
  {
    const float* xr = x + (size_t)(m0 + wv * 16 + l16) * DD;
#pragma unroll
    for (int c = 0; c < 8; ++c) {
      float4 a = *(const float4*)(xr + c * 32 + quad * 8);
      float4 b = *(const float4*)(xr + c * 32 + quad * 8 + 4);
      half8 v;
      v[0] = (_Float16)a.x; v[1] = (_Float16)a.y; v[2] = (_Float16)a.z; v[3] = (_Float16)a.w;
      v[4] = (_Float16)b.x; v[5] = (_Float16)b.y; v[6] = (_Float16)b.z; v[7] = (_Float16)b.w;
      xf[c] = v;
    }
  }

#pragma unroll 1
  for (int eg = 0; eg < 4; ++eg) {
    uint4 t0[8], t1[8];
    {
      const unsigned short* sh = wth + (size_t)(eg * 64) * DD;
      const unsigned short* sl = wtl + (size_t)(eg * 64) * DD;
#pragma unroll
      for (int i = 0; i < 8; ++i) {
        t0[i] = *(const uint4*)(sh + (i * 256 + tid) * 8);
        t1[i] = *(const uint4*)(sl + (i * 256 + tid) * 8);
      }
    }
    __syncthreads();
#pragma unroll
    for (int i = 0; i < 8; ++i) {
      *(uint4*)(wb[0] + (i * 256 + tid) * 8) = t0[i];
      *(uint4*)(wb[1] + (i * 256 + tid) * 8) = t1[i];
    }
    __syncthreads();
#pragma unroll
    for (int etl = 0; etl < 4; ++etl) {
      int rloc = etl * 16 + l16;
      f32x4 acc; acc[0] = acc[1] = acc[2] = acc[3] = 0.f;
#pragma unroll
      for (int c = 0; c < 8; ++c) {
        int off = rloc * DD + (((4 * c + quad) ^ (rloc & 7)) * 8);
        half8 wh = *(const half8*)(wb[0] + off);
        half8 wl = *(const half8*)(wb[1] + off);
        acc = __builtin_amdgcn_mfma_f32_16x16x32_f16(xf[c], wh, acc, 0, 0, 0);
        acc = __builtin_amdgcn_mfma_f32_16x16x32_f16(xf[c], wl, acc, 0, 0, 0);
      }
      int e = eg * 64 + etl * 16 + l16;
#pragma unroll
      for (int rg = 0; rg < 4; ++rg) {
        qf[(size_t)(m0 + wv * 16 + 4 * quad + rg) * DD + e] = f2h(acc[rg] * 1.44269504f);
      }
    }
  }
}

// ---------------- flash attention v14: j-split QK^T, pipelined f32 score exchange ----------------
// 4 waves = 2 pairs x 2 j/d-halves; pair owns 16 q. Wave h computes S^T(kt) for its
// j-half (8 MFMA, 8 K reads), writes raw f32 scores to sx[kt&1]; in the SAME body it
// consumes tile kt-1: own saved regs + partner's half from sx[(kt-1)&1] (visible via
// kt-1's barrier). Softmax+PV(kt-1) self-consistent per wave. ONE end-of-body barrier
// per kt: full-body cover for DMA K(kt+1) and sx(kt).
__global__ __launch_bounds__(256, 4) void attn_kernel(
    const unsigned short* __restrict__ kfrag, const unsigned short* __restrict__ vfrag,
    const unsigned short* __restrict__ qf, float* __restrict__ out) {
  __shared__ unsigned short kls[2][KVB * DD];   // 32 KB
  __shared__ uint4 sx[2][2][2][64];             // 8 KB [buf][pair][h][lane], raw f32 scores

  const int tid = threadIdx.x;
  const int lane = tid & 63;
  const int wv = tid >> 6;       // 0..3
  const int p = wv >> 1;         // pair
  const int h = wv & 1;          // j-half (QK^T) and d-half (PV)
  const int quad = lane >> 4;
  const int l16 = lane & 15;

  int bx = blockIdx.x;
  int lbx = (bx & 7) * 128 + (bx >> 3);   // XCD-chunked (1024 = 8*128)
  const int b = lbx >> 6;
  const int qbase = (lbx & 63) * 32 + p * 16;

  const unsigned short* kfb = kfrag + (size_t)b * NT * 8192;
  const unsigned short* vfb = vfrag + (size_t)b * NT * 8192 + h * 4096;

  // Q fragments (16 q, log2e-prescaled)
  half8 qh[8];
  {
    const size_t qrow = ((size_t)b * NI + qbase + l16) * DD;
#pragma unroll
    for (int c = 0; c < 8; ++c)
      qh[c] = *(const half8*)(qf + qrow + c * 32 + quad * 8);
  }

  f32x4 acc[8];
#pragma unroll
  for (int dt = 0; dt < 8; ++dt) { acc[dt][0] = 0.f; acc[dt][1] = 0.f; acc[dt][2] = 0.f; acc[dt][3] = 0.f; }
  float m0r = -INFINITY;   // running row max (log2 units)
  float l0 = 0.f;          // per-lane partial denominator
  f32x4 sprev;

  // prologue: DMA K tile 0 into kls[0]
#pragma unroll
  for (int i = 0; i < 4; ++i) {
    int off = (i * 4 + wv) * 512;
    gload16(kfb + off + lane * 8, &kls[0][off]);
  }
  __syncthreads();

#pragma unroll 1
  for (int kt = 0; kt < NT; ++kt) {
    // ---- V(kt-1) loads (own d-half), fully coalesced ----
    half8 vb[8];
    if (kt > 0) {
#pragma unroll
      for (int dt = 0; dt < 8; ++dt)
        vb[dt] = *(const half8*)(vfb + (size_t)(kt - 1) * 8192 + dt * 512 + lane * 8);
    }

    // ---- async DMA K(kt+1) (drained by this kt's end barrier: full-body cover) ----
    if (kt + 1 < NT) {
      const unsigned short* s = kfb + (size_t)(kt + 1) * 8192;
      unsigned short* d = &kls[(kt + 1) & 1][0];
#pragma unroll
      for (int i = 0; i < 4; ++i) {
        int off = (i * 4 + wv) * 512;
        gload16(s + off + lane * 8, d + off);
      }
    }

    // ---- QK^T(kt): own j-half only (16 j x 16 q), split chains ----
    const unsigned short* kb = &kls[kt & 1][0];
    f32x4 sa, sb;
    sa[0]=sa[1]=sa[2]=sa[3]=0.f; sb[0]=sb[1]=sb[2]=sb[3]=0.f;
    __builtin_amdgcn_s_setprio(1);
#pragma unroll
    for (int c = 0; c < 4; ++c) {
      half8 k0 = *(const half8*)(kb + c * 1024 + h * 512 + lane * 8);
      sa = __builtin_amdgcn_mfma_f32_16x16x32_f16(k0, qh[c], sa, 0, 0, 0);
    }
#pragma unroll
    for (int c = 4; c < 8; ++c) {
      half8 k0 = *(const half8*)(kb + c * 1024 + h * 512 + lane * 8);
      sb = __builtin_amdgcn_mfma_f32_16x16x32_f16(k0, qh[c], sb, 0, 0, 0);
    }
    __builtin_amdgcn_s_setprio(0);
    f32x4 s;
    s[0] = sa[0] + sb[0]; s[1] = sa[1] + sb[1];
    s[2] = sa[2] + sb[2]; s[3] = sa[3] + sb[3];

    // ---- write own raw f32 scores for partner (consumed next iteration) ----
    sx[kt & 1][p][h][lane] = make_uint4(f2u(s[0]), f2u(s[1]), f2u(s[2]), f2u(s[3]));

    // ---- process tile kt-1: own sprev + partner's half ----
    if (kt > 0) {
      uint4 ox = sx[(kt - 1) & 1][p][h ^ 1][lane];
      float o0 = u2f(ox.x), o1 = u2f(ox.y), o2 = u2f(ox.z), o3 = u2f(ox.w);

      float mt = fmaxf(fmaxf(fmaxf(sprev[0], sprev[1]), fmaxf(sprev[2], sprev[3])),
                       fmaxf(fmaxf(o0, o1), fmaxf(o2, o3)));
      if (__any(mt > m0r + 11.5416f)) {       // 8 nats in log2 units
        float mr = fmaxf(mt, __shfl_xor(mt, 16));
        mr = fmaxf(mr, __shfl_xor(mr, 32));
        float mn = fmaxf(m0r, mr);
        float sc = exp2f(m0r - mn);
        l0 *= sc;
#pragma unroll
        for (int rg = 0; rg < 4; ++rg) {
          float a0 = __shfl(sc, 4 * quad + rg);
#pragma unroll
          for (int dt = 0; dt < 8; ++dt) acc[dt][rg] *= a0;
        }
        m0r = mn;
      }

      float es0 = exp2f(sprev[0] - m0r), es1 = exp2f(sprev[1] - m0r);
      float es2 = exp2f(sprev[2] - m0r), es3 = exp2f(sprev[3] - m0r);
      float eo0 = exp2f(o0 - m0r), eo1 = exp2f(o1 - m0r);
      float eo2 = exp2f(o2 - m0r), eo3 = exp2f(o3 - m0r);
      l0 += ((es0 + es1) + (es2 + es3)) + ((eo0 + eo1) + (eo2 + eo3));
      unsigned int d0 = pk2(es0, es1), d1 = pk2(es2, es3);
      unsigned int c0 = pk2(eo0, eo1), c1 = pk2(eo2, eo3);
      uint4v pau;
      if (h == 0) { pau[0] = d0; pau[1] = d1; pau[2] = c0; pau[3] = c1; }
      else        { pau[0] = c0; pau[1] = c1; pau[2] = d0; pau[3] = d1; }
      half8 pa = __builtin_bit_cast(half8, pau);

      __builtin_amdgcn_s_setprio(1);
#pragma unroll
      for (int dt = 0; dt < 8; ++dt)
        acc[dt] = __builtin_amdgcn_mfma_f32_16x16x32_f16(pa, vb[dt], acc[dt], 0, 0, 0);
      __builtin_amdgcn_s_setprio(0);
    }
    sprev = s;
    __syncthreads();   // drains DMA(kt+1) + makes sx(kt) visible
  }

  // ---- tail: process tile NT-1 ----
  {
    half8 vb[8];
#pragma unroll
    for (int dt = 0; dt < 8; ++dt)
      vb[dt] = *(const half8*)(vfb + (size_t)(NT - 1) * 8192 + dt * 512 + lane * 8);
    uint4 ox = sx[(NT - 1) & 1][p][h ^ 1][lane];
    float o0 = u2f(ox.x), o1 = u2f(ox.y), o2 = u2f(ox.z), o3 = u2f(ox.w);
    float mt = fmaxf(fmaxf(fmaxf(sprev[0], sprev[1]), fmaxf(sprev[2], sprev[3])),
                     fmaxf(fmaxf(o0, o1), fmaxf(o2, o3)));
    if (__any(mt > m0r + 11.5416f)) {
      float mr = fmaxf(mt, __shfl_xor(mt, 16));
      mr = fmaxf(mr, __shfl_xor(mr, 32));
      float mn = fmaxf(m0r, mr);
      float sc = exp2f(m0r - mn);
      l0 *= sc;
#pragma unroll
      for (int rg = 0; rg < 4; ++rg) {
        float a0 = __shfl(sc, 4 * quad + rg);
#pragma unroll
        for (int dt = 0; dt < 8; ++dt) acc[dt][rg] *= a0;
      }
      m0r = mn;
    }
    float es0 = exp2f(sprev[0] - m0r), es1 = exp2f(sprev[1] - m0r);
    float es2 = exp2f(sprev[2] - m0r), es3 = exp2f(sprev[3] - m0r);
    float eo0 = exp2f(o0 - m0r), eo1 = exp2f(o1 - m0r);
    float eo2 = exp2f(o2 - m0r), eo3 = exp2f(o3 - m0r);
    l0 += ((es0 + es1) + (es2 + es3)) + ((eo0 + eo1) + (eo2 + eo3));
    unsigned int d0 = pk2(es0, es1), d1 = pk2(es2, es3);
    unsigned int c0 = pk2(eo0, eo1), c1 = pk2(eo2, eo3);
    uint4v pau;
    if (h == 0) { pau[0] = d0; pau[1] = d1; pau[2] = c0; pau[3] = c1; }
    else        { pau[0] = c0; pau[1] = c1; pau[2] = d0; pau[3] = d1; }
    half8 pa = __builtin_bit_cast(half8, pau);
#pragma unroll
    for (int dt = 0; dt < 8; ++dt)
      acc[dt] = __builtin_amdgcn_mfma_f32_16x16x32_f16(pa, vb[dt], acc[dt], 0, 0, 0);
  }

  // ---- epilogue ----
  l0 += __shfl_xor(l0, 16); l0 += __shfl_xor(l0, 32);
  float inv0 = 1.0f / l0;
  size_t ob = ((size_t)b * NI + qbase) * DD + h * 128;
#pragma unroll
  for (int rg = 0; rg < 4; ++rg) {
    float i0 = __shfl(inv0, 4 * quad + rg);
#pragma unroll
    for (int dt = 0; dt < 8; ++dt) {
      int d = dt * 16 + l16;
      out[ob + (size_t)(4 * quad + rg) * DD + d] = acc[dt][rg] * i0;
    }
  }
}

extern "C" void kernel_launch(void* const* d_in, const int* in_sizes, int n_in,
                              void* d_out, int out_size, void* d_ws, size_t ws_size,
                              hipStream_t stream) {
  const float* x = (const float*)d_in[0];        // [16,2048,256]
  const float* att = (const float*)d_in[1];      // [16,2048,256]
  const float* W = (const float*)d_in[2];        // [256,256]
  float* out = (float*)d_out;

  const size_t NE = (size_t)BB * NA * DD;        // 8388608
  unsigned short* w0    = (unsigned short*)d_ws;
  unsigned short* kfrag = w0;
  unsigned short* vfrag = w0 + NE;
  unsigned short* qfp   = w0 + 2 * NE;
  unsigned short* wth   = w0 + 3 * NE;
  unsigned short* wtl   = w0 + 3 * NE + (size_t)DD * DD;

  prep_kernel<<<2064, 256, 0, stream>>>(att, kfrag, vfrag, W, wth, wtl);
  qgemm_kernel<<<512, 256, 0, stream>>>(x, wth, wtl, qfp);
  attn_kernel<<<1024, 256, 0, stream>>>(kfrag, vfrag, qfp, out);
}

// Round 15
// 197.591 us; speedup vs baseline: 1.0697x; 1.0697x over previous
//
#include <hip/hip_runtime.h>
#include <hip/hip_bf16.h>

#define BB 16
#define NI 2048
#define NA 2048
#define DD 256
#define KVB 32
#define NT (NA / KVB)    // 64

typedef _Float16 half8 __attribute__((ext_vector_type(8)));
typedef __attribute__((ext_vector_type(4))) float f32x4;
typedef __attribute__((ext_vector_type(4))) unsigned int uint4v;

typedef const unsigned int CGU __attribute__((address_space(1)));
typedef unsigned int LU __attribute__((address_space(3)));

static __device__ __forceinline__ unsigned short f2h(float f) {
  union { _Float16 h; unsigned short u; } x; x.h = (_Float16)f; return x.u;
}
static __device__ __forceinline__ float h2f(unsigned short u) {
  union { _Float16 h; unsigned short u; } x; x.u = u; return (float)x.h;
}
static __device__ __forceinline__ unsigned int pk2(float a, float b) {
  return __builtin_bit_cast(unsigned int, __builtin_amdgcn_cvt_pkrtz(a, b));
}
static __device__ __forceinline__ float ex2(float x) {
  return __builtin_amdgcn_exp2f(x);   // raw v_exp_f32: 2^x
}
// async global->LDS, 16B/lane; dst is wave-uniform base (HW adds lane*16)
static __device__ __forceinline__ void gload16(const unsigned short* g, unsigned short* l) {
  __builtin_amdgcn_global_load_lds((CGU*)g, (LU*)l, 16, 0, 0);
}

// ---------------- prep (+fused tw): attendee -> kfrag + vfrag; W -> wth/wtl ----------------
// kfrag[b][kt][c(8)][jt(2)][lane(64)][e(8)]: lane=quad*16+l16 holds K[jb+jt*16+l16][c*32+quad*8+e]
// vfrag[b][kt][h(2)][dt(8)][lane(64)][e(8)]: lane holds V^T[h*128+dt*16+l16][jb + pi(quad,e)]
//   pi(quad,e) = (e>>2)*16 + 4*quad + (e&3)  — matches P's natural post-QK^T layout.
__global__ void prep_kernel(const float* __restrict__ a,
                            unsigned short* __restrict__ kfrag,
                            unsigned short* __restrict__ vfrag,
                            const float* __restrict__ w,
                            unsigned short* __restrict__ wth,
                            unsigned short* __restrict__ wtl) {
  __shared__ float t[64][65];
  int bx = blockIdx.x;
  int tid = threadIdx.x;
  int rr = tid >> 4, c4 = tid & 15;

  if (bx >= 2048) {
    // ---- tw: W -> W^T hi/lo fp16, row-XOR-swizzled [e][d] ----
    int r = bx - 2048;
    int dt = r >> 2, et = r & 3;
    int d0 = dt * 64, e0 = et * 64;
    int cc = c4 * 4;
#pragma unroll
    for (int k = 0; k < 4; ++k) {
      int row = rr + k * 16;   // d index
      float4 v = *(const float4*)(w + (size_t)(d0 + row) * DD + e0 + cc);
      t[row][cc + 0] = v.x; t[row][cc + 1] = v.y; t[row][cc + 2] = v.z; t[row][cc + 3] = v.w;
    }
    __syncthreads();
#pragma unroll
    for (int k = 0; k < 4; ++k) {
      int e = rr + k * 16;
      int eg = e0 + e;
      ushort4 h, l;
      float v0 = t[cc + 0][e]; h.x = f2h(v0); l.x = f2h(v0 - h2f(h.x));
      float v1 = t[cc + 1][e]; h.y = f2h(v1); l.y = f2h(v1 - h2f(h.y));
      float v2 = t[cc + 2][e]; h.z = f2h(v2); l.z = f2h(v2 - h2f(h.z));
      float v3 = t[cc + 3][e]; h.w = f2h(v3); l.w = f2h(v3 - h2f(h.w));
      int dd = d0 + cc;
      int u = dd >> 3, sub = dd & 7;
      size_t off = (size_t)eg * DD + ((u ^ (eg & 7)) * 8) + sub;
      *(ushort4*)(wth + off) = h;
      *(ushort4*)(wtl + off) = l;
    }
    return;
  }

  int b = bx >> 7;
  int r = bx & 127;
  int jt_t = r >> 2, dt_t = r & 3;
  int j0 = jt_t * 64, d0 = dt_t * 64;
#pragma unroll
  for (int k = 0; k < 4; ++k) {
    int row = rr + k * 16;
    int j = j0 + row;
    int d = d0 + c4 * 4;
    float4 v = *(const float4*)(a + ((size_t)b * NA + j) * DD + d);
    ushort4 hh;
    hh.x = f2h(v.x); hh.y = f2h(v.y); hh.z = f2h(v.z); hh.w = f2h(v.w);
    int kt = j >> 5, jtf = (j >> 4) & 1, l16k = j & 15;
    int c = d >> 5, quad = (d >> 3) & 3, e = d & 7;
    *(ushort4*)(kfrag + ((size_t)b * NT + kt) * 8192 + c * 1024 + jtf * 512 +
                (quad * 16 + l16k) * 8 + e) = hh;
    t[row][c4 * 4 + 0] = v.x; t[row][c4 * 4 + 1] = v.y;
    t[row][c4 * 4 + 2] = v.z; t[row][c4 * 4 + 3] = v.w;
  }
  __syncthreads();
#pragma unroll
  for (int k = 0; k < 4; ++k) {
    int dl = rr + k * 16;
    int d = d0 + dl;
    int j = j0 + c4 * 4;              // 4 consecutive j
    ushort4 o;
    o.x = f2h(t[c4 * 4 + 0][dl]); o.y = f2h(t[c4 * 4 + 1][dl]);
    o.z = f2h(t[c4 * 4 + 2][dl]); o.w = f2h(t[c4 * 4 + 3][dl]);
    int kt = j >> 5;
    int quad = c4 & 3;                // pi-inverse: j=j0+4*c4+i -> quad=c4&3
    int jt = (c4 >> 2) & 1;           // e = jt*4 + i
    int hh_ = (d >> 7) & 1, dtl = (d >> 4) & 7, l16v = d & 15;
    *(ushort4*)(vfrag + ((size_t)b * NT + kt) * 8192 + hh_ * 4096 + dtl * 512 +
                (quad * 16 + l16v) * 8 + jt * 4) = o;
  }
}

// ---------------- Q = (x @ W) * log2(e)  (2-term fp16 MFMA), writes qf fp16 row-major ----------------
__global__ __launch_bounds__(256, 2) void qgemm_kernel(
    const float* __restrict__ x, const unsigned short* __restrict__ wth,
    const unsigned short* __restrict__ wtl, unsigned short* __restrict__ qf) {
  __shared__ unsigned short wb[2][64 * 256];   // 64 KB
  const int tid = threadIdx.x;
  const int lane = tid & 63;
  const int wv = tid >> 6;
  const int quad = lane >> 4;
  const int l16 = lane & 15;
  const int m0 = blockIdx.x * 64;

  half8 xf[8];
  {
    const float* xr = x + (size_t)(m0 + wv * 16 + l16) * DD;
#pragma unroll
    for (int c = 0; c < 8; ++c) {
      float4 a = *(const float4*)(xr + c * 32 + quad * 8);
      float4 b = *(const float4*)(xr + c * 32 + quad * 8 + 4);
      half8 v;
      v[0] = (_Float16)a.x; v[1] = (_Float16)a.y; v[2] = (_Float16)a.z; v[3] = (_Float16)a.w;
      v[4] = (_Float16)b.x; v[5] = (_Float16)b.y; v[6] = (_Float16)b.z; v[7] = (_Float16)b.w;
      xf[c] = v;
    }
  }

#pragma unroll 1
  for (int eg = 0; eg < 4; ++eg) {
    uint4 t0[8], t1[8];
    {
      const unsigned short* sh = wth + (size_t)(eg * 64) * DD;
      const unsigned short* sl = wtl + (size_t)(eg * 64) * DD;
#pragma unroll
      for (int i = 0; i < 8; ++i) {
        t0[i] = *(const uint4*)(sh + (i * 256 + tid) * 8);
        t1[i] = *(const uint4*)(sl + (i * 256 + tid) * 8);
      }
    }
    __syncthreads();
#pragma unroll
    for (int i = 0; i < 8; ++i) {
      *(uint4*)(wb[0] + (i * 256 + tid) * 8) = t0[i];
      *(uint4*)(wb[1] + (i * 256 + tid) * 8) = t1[i];
    }
    __syncthreads();
#pragma unroll
    for (int etl = 0; etl < 4; ++etl) {
      int rloc = etl * 16 + l16;
      f32x4 acc; acc[0] = acc[1] = acc[2] = acc[3] = 0.f;
#pragma unroll
      for (int c = 0; c < 8; ++c) {
        int off = rloc * DD + (((4 * c + quad) ^ (rloc & 7)) * 8);
        half8 wh = *(const half8*)(wb[0] + off);
        half8 wl = *(const half8*)(wb[1] + off);
        acc = __builtin_amdgcn_mfma_f32_16x16x32_f16(xf[c], wh, acc, 0, 0, 0);
        acc = __builtin_amdgcn_mfma_f32_16x16x32_f16(xf[c], wl, acc, 0, 0, 0);
      }
      int e = eg * 64 + etl * 16 + l16;
#pragma unroll
      for (int rg = 0; rg < 4; ++rg) {
        qf[(size_t)(m0 + wv * 16 + 4 * quad + rg) * DD + e] = f2h(acc[rg] * 1.44269504f);
      }
    }
  }
}

// ---------------- flash attention v15: v12 structure + native exp2 + addr hygiene ----------------
// 4 waves = 2 pairs x 2 d-halves; pair owns 16 q (QK^T duplicated in pair, PV splits d).
// K double-buffered via async global_load_lds (one end-of-body barrier/kt = full cover).
// V coalesced to regs; P packed in-register (co-permuted vfrag). Native v_exp_f32.
__global__ __launch_bounds__(256, 4) void attn_kernel(
    const unsigned short* __restrict__ kfrag, const unsigned short* __restrict__ vfrag,
    const unsigned short* __restrict__ qf, float* __restrict__ out) {
  __shared__ unsigned short kls[2][KVB * DD];   // 2 x 16 KB

  const int tid = threadIdx.x;
  const int lane = tid & 63;
  const int wv = tid >> 6;       // 0..3
  const int p = wv >> 1;         // pair
  const int h = wv & 1;          // d-half
  const int quad = lane >> 4;
  const int l16 = lane & 15;

  int bx = blockIdx.x;
  int lbx = (bx & 7) * 128 + (bx >> 3);   // XCD-chunked (1024 = 8*128)
  const int b = lbx >> 6;
  const int qbase = (lbx & 63) * 32 + p * 16;

  const unsigned short* kfb = kfrag + (size_t)b * NT * 8192;

  // Q fragments (16 q, log2e-prescaled)
  half8 qh[8];
  {
    const size_t qrow = ((size_t)b * NI + qbase + l16) * DD;
#pragma unroll
    for (int c = 0; c < 8; ++c)
      qh[c] = *(const half8*)(qf + qrow + c * 32 + quad * 8);
  }

  f32x4 acc[8];
#pragma unroll
  for (int dt = 0; dt < 8; ++dt) { acc[dt][0] = 0.f; acc[dt][1] = 0.f; acc[dt][2] = 0.f; acc[dt][3] = 0.f; }
  float m0r = -INFINITY;   // running row max (log2 units)
  float l0 = 0.f;          // per-lane partial denominator

  // loop-carried pointers (encourage SGPR-base + imm addressing, no per-kt 64b VALU)
  const unsigned short* vp = vfrag + (size_t)b * NT * 8192 + h * 4096 + lane * 8;
  const unsigned short* sp = kfb + 8192 + (wv * 512 + lane * 8);   // DMA src for kt+1

  // prologue: DMA K tile 0 into kls[0]
#pragma unroll
  for (int i = 0; i < 4; ++i) {
    int off = (i * 4 + wv) * 512;
    gload16(kfb + off + lane * 8, &kls[0][off]);
  }
  __syncthreads();

#pragma unroll 1
  for (int kt = 0; kt < NT; ++kt) {
    // ---- V loads (own d-half), fully coalesced; consumed in PV at end ----
    half8 vb[8];
#pragma unroll
    for (int dt = 0; dt < 8; ++dt)
      vb[dt] = *(const half8*)(vp + dt * 512);

    // ---- async DMA K(kt+1) (drained by end-of-body barrier: full-body cover) ----
    if (kt + 1 < NT) {
      unsigned short* d = &kls[(kt + 1) & 1][wv * 512];
      gload16(sp + 0 * 2048, d + 0 * 2048);
      gload16(sp + 1 * 2048, d + 1 * 2048);
      gload16(sp + 2 * 2048, d + 2 * 2048);
      gload16(sp + 3 * 2048, d + 3 * 2048);
    }

    // ---- QK^T: S^T[32 j x 16 q] from contiguous LDS frags (2 chains) ----
    const unsigned short* kb = &kls[kt & 1][0];
    f32x4 st0, st1;
    st0[0] = st0[1] = st0[2] = st0[3] = 0.f;
    st1[0] = st1[1] = st1[2] = st1[3] = 0.f;
    __builtin_amdgcn_s_setprio(1);
#pragma unroll
    for (int c = 0; c < 8; ++c) {
      half8 k0 = *(const half8*)(kb + c * 1024 + lane * 8);         // jt=0
      half8 k1 = *(const half8*)(kb + c * 1024 + 512 + lane * 8);   // jt=1
      st0 = __builtin_amdgcn_mfma_f32_16x16x32_f16(k0, qh[c], st0, 0, 0, 0);
      st1 = __builtin_amdgcn_mfma_f32_16x16x32_f16(k1, qh[c], st1, 0, 0, 0);
    }
    __builtin_amdgcn_s_setprio(0);

    // ---- defer-max fast path: lane-local check; full reduce only on update ----
    float mt = fmaxf(fmaxf(fmaxf(st0[0], st0[1]), fmaxf(st0[2], st0[3])),
                     fmaxf(fmaxf(st1[0], st1[1]), fmaxf(st1[2], st1[3])));
    if (__any(mt > m0r + 11.5416f)) {       // 8 nats in log2 units
      float mr = fmaxf(mt, __shfl_xor(mt, 16));
      mr = fmaxf(mr, __shfl_xor(mr, 32));
      float mn = fmaxf(m0r, mr);
      float sc = ex2(m0r - mn);
      l0 *= sc;
#pragma unroll
      for (int rg = 0; rg < 4; ++rg) {
        float a0 = __shfl(sc, 4 * quad + rg);
#pragma unroll
        for (int dt = 0; dt < 8; ++dt) acc[dt][rg] *= a0;
      }
      m0r = mn;
    }

    // ---- native exp2 + per-lane partial sum + in-register P pack ----
    float e00 = ex2(st0[0] - m0r), e01 = ex2(st0[1] - m0r);
    float e02 = ex2(st0[2] - m0r), e03 = ex2(st0[3] - m0r);
    float e10 = ex2(st1[0] - m0r), e11 = ex2(st1[1] - m0r);
    float e12 = ex2(st1[2] - m0r), e13 = ex2(st1[3] - m0r);
    l0 += ((e00 + e01) + (e02 + e03)) + ((e10 + e11) + (e12 + e13));
    half8 pa;
    {
      uint4v pau = { pk2(e00, e01), pk2(e02, e03), pk2(e10, e11), pk2(e12, e13) };
      pa = __builtin_bit_cast(half8, pau);
    }

    // ---- PV (own d-half) ----
    __builtin_amdgcn_s_setprio(1);
#pragma unroll
    for (int dt = 0; dt < 8; ++dt)
      acc[dt] = __builtin_amdgcn_mfma_f32_16x16x32_f16(pa, vb[dt], acc[dt], 0, 0, 0);
    __builtin_amdgcn_s_setprio(0);

    vp += 8192;
    sp += 8192;
    __syncthreads();   // drains DMA for kt+1
  }

  // ---- epilogue: reduce denominator, normalize, store ----
  l0 += __shfl_xor(l0, 16); l0 += __shfl_xor(l0, 32);
  float inv0 = 1.0f / l0;
  size_t ob = ((size_t)b * NI + qbase) * DD + h * 128;
#pragma unroll
  for (int rg = 0; rg < 4; ++rg) {
    float i0 = __shfl(inv0, 4 * quad + rg);
#pragma unroll
    for (int dt = 0; dt < 8; ++dt) {
      int d = dt * 16 + l16;
      out[ob + (size_t)(4 * quad + rg) * DD + d] = acc[dt][rg] * i0;
    }
  }
}

extern "C" void kernel_launch(void* const* d_in, const int* in_sizes, int n_in,
                              void* d_out, int out_size, void* d_ws, size_t ws_size,
                              hipStream_t stream) {
  const float* x = (const float*)d_in[0];        // [16,2048,256]
  const float* att = (const float*)d_in[1];      // [16,2048,256]
  const float* W = (const float*)d_in[2];        // [256,256]
  float* out = (float*)d_out;

  const size_t NE = (size_t)BB * NA * DD;        // 8388608
  unsigned short* w0    = (unsigned short*)d_ws;
  unsigned short* kfrag = w0;
  unsigned short* vfrag = w0 + NE;
  unsigned short* qfp   = w0 + 2 * NE;
  unsigned short* wth   = w0 + 3 * NE;
  unsigned short* wtl   = w0 + 3 * NE + (size_t)DD * DD;

  prep_kernel<<<2064, 256, 0, stream>>>(att, kfrag, vfrag, W, wth, wtl);
  qgemm_kernel<<<512, 256, 0, stream>>>(x, wth, wtl, qfp);
  attn_kernel<<<1024, 256, 0, stream>>>(kfrag, vfrag, qfp, out);
}

// Round 16
// 182.658 us; speedup vs baseline: 1.1572x; 1.0818x over previous
//
#include <hip/hip_runtime.h>
#include <hip/hip_bf16.h>

#define BB 16
#define NI 2048
#define NA 2048
#define DD 256
#define KVB 32
#define NT (NA / KVB)    // 64

typedef _Float16 half8 __attribute__((ext_vector_type(8)));
typedef __attribute__((ext_vector_type(16))) float f32x16;
typedef __attribute__((ext_vector_type(4))) unsigned int uint4v;

typedef const unsigned int CGU __attribute__((address_space(1)));
typedef unsigned int LU __attribute__((address_space(3)));

static __device__ __forceinline__ unsigned short f2h(float f) {
  union { _Float16 h; unsigned short u; } x; x.h = (_Float16)f; return x.u;
}
static __device__ __forceinline__ float h2f(unsigned short u) {
  union { _Float16 h; unsigned short u; } x; x.u = u; return (float)x.h;
}
static __device__ __forceinline__ unsigned int pk2(float a, float b) {
  return __builtin_bit_cast(unsigned int, __builtin_amdgcn_cvt_pkrtz(a, b));
}
static __device__ __forceinline__ float ex2(float x) {
  return __builtin_amdgcn_exp2f(x);
}
static __device__ __forceinline__ void gload16(const unsigned short* g, unsigned short* l) {
  __builtin_amdgcn_global_load_lds((CGU*)g, (LU*)l, 16, 0, 0);
}

// ---------------- prep (+fused tw) ----------------
// kfrag[b][kt][ks(16)][lane(64)][e(8)]: lane holds K[jb + (l&31)][ks*16 + (l>>5)*8 + e]
//   (A-operand of mfma_32x32x16: row j = l&31, k-slot = (l>>5)*8+e)
// vfrag[b][kt][h(2)][dt(4)][m(2)][lane(64)][e(8)]: lane holds
//   V^T[h*128 + dt*32 + (l&31)][jb + (e&3) + 8*(e>>2) + 4*(l>>5) + 16*m]
//   (A-operand rows d; k-slot j-map co-permuted with P's B-frag pack)
__global__ void prep_kernel(const float* __restrict__ a,
                            unsigned short* __restrict__ kfrag,
                            unsigned short* __restrict__ vfrag,
                            const float* __restrict__ w,
                            unsigned short* __restrict__ wth,
                            unsigned short* __restrict__ wtl) {
  __shared__ float t[64][65];
  int bx = blockIdx.x;
  int tid = threadIdx.x;
  int rr = tid >> 4, c4 = tid & 15;

  if (bx >= 2048) {
    int r = bx - 2048;
    int dt = r >> 2, et = r & 3;
    int d0 = dt * 64, e0 = et * 64;
    int cc = c4 * 4;
#pragma unroll
    for (int k = 0; k < 4; ++k) {
      int row = rr + k * 16;
      float4 v = *(const float4*)(w + (size_t)(d0 + row) * DD + e0 + cc);
      t[row][cc + 0] = v.x; t[row][cc + 1] = v.y; t[row][cc + 2] = v.z; t[row][cc + 3] = v.w;
    }
    __syncthreads();
#pragma unroll
    for (int k = 0; k < 4; ++k) {
      int e = rr + k * 16;
      int eg = e0 + e;
      ushort4 h, l;
      float v0 = t[cc + 0][e]; h.x = f2h(v0); l.x = f2h(v0 - h2f(h.x));
      float v1 = t[cc + 1][e]; h.y = f2h(v1); l.y = f2h(v1 - h2f(h.y));
      float v2 = t[cc + 2][e]; h.z = f2h(v2); l.z = f2h(v2 - h2f(h.z));
      float v3 = t[cc + 3][e]; h.w = f2h(v3); l.w = f2h(v3 - h2f(h.w));
      int dd = d0 + cc;
      int u = dd >> 3, sub = dd & 7;
      size_t off = (size_t)eg * DD + ((u ^ (eg & 7)) * 8) + sub;
      *(ushort4*)(wth + off) = h;
      *(ushort4*)(wtl + off) = l;
    }
    return;
  }

  int b = bx >> 7;
  int r = bx & 127;
  int jt_t = r >> 2, dt_t = r & 3;
  int j0 = jt_t * 64, d0 = dt_t * 64;
#pragma unroll
  for (int k = 0; k < 4; ++k) {
    int row = rr + k * 16;
    int j = j0 + row;
    int d = d0 + c4 * 4;           // k-index for kfrag
    float4 v = *(const float4*)(a + ((size_t)b * NA + j) * DD + d);
    ushort4 hh;
    hh.x = f2h(v.x); hh.y = f2h(v.y); hh.z = f2h(v.z); hh.w = f2h(v.w);
    int kt = j >> 5;
    int ks = d >> 4;
    int lk = (j & 31) + 32 * ((d >> 3) & 1);
    *(ushort4*)(kfrag + (((size_t)b * NT + kt) * 16 + ks) * 512 + lk * 8 + (c4 & 1) * 4) = hh;
    t[row][c4 * 4 + 0] = v.x; t[row][c4 * 4 + 1] = v.y;
    t[row][c4 * 4 + 2] = v.z; t[row][c4 * 4 + 3] = v.w;
  }
  __syncthreads();
#pragma unroll
  for (int k = 0; k < 4; ++k) {
    int dl = rr + k * 16;
    int d = d0 + dl;
    int j = j0 + c4 * 4;           // 4 consecutive j
    ushort4 o;
    o.x = f2h(t[c4 * 4 + 0][dl]); o.y = f2h(t[c4 * 4 + 1][dl]);
    o.z = f2h(t[c4 * 4 + 2][dl]); o.w = f2h(t[c4 * 4 + 3][dl]);
    int kt = j >> 5;
    int hi = c4 & 1;               // (jj>>2)&1
    int m = (c4 >> 2) & 1;         // (jj>>4)&1
    int ebase = ((c4 >> 1) & 1) * 4;
    int hh_ = d >> 7, dtl = (d >> 5) & 3;
    int lv = (d & 31) + 32 * hi;
    *(ushort4*)(vfrag + ((((((size_t)b * NT + kt) * 2 + hh_) * 4 + dtl) * 2 + m) * 512) + lv * 8 + ebase) = o;
  }
}

// ---------------- Q = (x @ W) * log2(e) (2-term fp16 MFMA), qf row-major ----------------
__global__ __launch_bounds__(256, 2) void qgemm_kernel(
    const float* __restrict__ x, const unsigned short* __restrict__ wth,
    const unsigned short* __restrict__ wtl, unsigned short* __restrict__ qf) {
  __shared__ unsigned short wb[2][64 * 256];
  const int tid = threadIdx.x;
  const int lane = tid & 63;
  const int wv = tid >> 6;
  const int quad = lane >> 4;
  const int l16 = lane & 15;
  const int m0 = blockIdx.x * 64;

  half8 xf[8];
  {
    const float* xr = x + (size_t)(m0 + wv * 16 + l16) * DD;
#pragma unroll
    for (int c = 0; c < 8; ++c) {
      float4 a = *(const float4*)(xr + c * 32 + quad * 8);
      float4 b = *(const float4*)(xr + c * 32 + quad * 8 + 4);
      half8 v;
      v[0] = (_Float16)a.x; v[1] = (_Float16)a.y; v[2] = (_Float16)a.z; v[3] = (_Float16)a.w;
      v[4] = (_Float16)b.x; v[5] = (_Float16)b.y; v[6] = (_Float16)b.z; v[7] = (_Float16)b.w;
      xf[c] = v;
    }
  }

#pragma unroll 1
  for (int eg = 0; eg < 4; ++eg) {
    uint4 t0[8], t1[8];
    {
      const unsigned short* sh = wth + (size_t)(eg * 64) * DD;
      const unsigned short* sl = wtl + (size_t)(eg * 64) * DD;
#pragma unroll
      for (int i = 0; i < 8; ++i) {
        t0[i] = *(const uint4*)(sh + (i * 256 + tid) * 8);
        t1[i] = *(const uint4*)(sl + (i * 256 + tid) * 8);
      }
    }
    __syncthreads();
#pragma unroll
    for (int i = 0; i < 8; ++i) {
      *(uint4*)(wb[0] + (i * 256 + tid) * 8) = t0[i];
      *(uint4*)(wb[1] + (i * 256 + tid) * 8) = t1[i];
    }
    __syncthreads();
#pragma unroll
    for (int etl = 0; etl < 4; ++etl) {
      int rloc = etl * 16 + l16;
      float4 acc4 = make_float4(0.f, 0.f, 0.f, 0.f);
      typedef __attribute__((ext_vector_type(4))) float f32x4;
      f32x4 acc; acc[0] = acc[1] = acc[2] = acc[3] = 0.f;
#pragma unroll
      for (int c = 0; c < 8; ++c) {
        int off = rloc * DD + (((4 * c + quad) ^ (rloc & 7)) * 8);
        half8 wh = *(const half8*)(wb[0] + off);
        half8 wl = *(const half8*)(wb[1] + off);
        acc = __builtin_amdgcn_mfma_f32_16x16x32_f16(xf[c], wh, acc, 0, 0, 0);
        acc = __builtin_amdgcn_mfma_f32_16x16x32_f16(xf[c], wl, acc, 0, 0, 0);
      }
      (void)acc4;
      int e = eg * 64 + etl * 16 + l16;
#pragma unroll
      for (int rg = 0; rg < 4; ++rg) {
        qf[(size_t)(m0 + wv * 16 + 4 * quad + rg) * DD + e] = f2h(acc[rg] * 1.44269504f);
      }
    }
  }
}

// ---------------- flash attention v16: 32x32 MFMA, pair owns 32q, d-split PV ----------------
// 4 waves = 2 pairs x 2 d-halves; each wave computes full 32x32 S^T (16 big MFMA,
// 16 K b128 reads -> per-q LDS reads halved), softmax fully in-lane (q = lane&31,
// one shfl_xor(32)), PV via co-permuted vfrag (zero-shuffle P). K DMA double-buffered,
// one end-of-body barrier/kt. 2 blocks/CU.
__global__ __launch_bounds__(256, 2) void attn_kernel(
    const unsigned short* __restrict__ kfrag, const unsigned short* __restrict__ vfrag,
    const unsigned short* __restrict__ qf, float* __restrict__ out) {
  __shared__ unsigned short kls[2][KVB * DD];   // 2 x 16 KB

  const int tid = threadIdx.x;
  const int lane = tid & 63;
  const int wv = tid >> 6;       // 0..3
  const int pr = wv >> 1;        // pair -> q-group
  const int h = wv & 1;          // d-half
  const int l31 = lane & 31;
  const int hi = lane >> 5;

  int bx = blockIdx.x;
  int lbx = (bx & 7) * 64 + (bx >> 3);   // XCD-chunked (512 = 8*64)
  const int b = lbx >> 5;
  const int qbase = (lbx & 31) * 64 + pr * 32;

  const unsigned short* kfb = kfrag + (size_t)b * NT * 8192;

  // Q B-fragments (32 q x 256 k): lane holds col q=l31, k = ks*16 + hi*8 + e
  half8 qh[16];
  {
    const unsigned short* qr = qf + ((size_t)b * NI + qbase + l31) * DD + hi * 8;
#pragma unroll
    for (int ks = 0; ks < 16; ++ks)
      qh[ks] = *(const half8*)(qr + ks * 16);
  }

  f32x16 acc[4];
#pragma unroll
  for (int dt = 0; dt < 4; ++dt)
#pragma unroll
    for (int i = 0; i < 16; ++i) acc[dt][i] = 0.f;
  float m0r = -INFINITY;   // running row max (log2 units) for q = l31
  float l0 = 0.f;          // per-lane partial denominator

  // loop-carried pointers
  const unsigned short* vp = vfrag + (((size_t)b * NT * 2 + h) * 4) * 1024 + lane * 8;
  // per-kt stride for vfrag = 8192 shorts; vb[idx] at idx*512
  const unsigned short* sp = kfb + 8192 + (wv * 512 + lane * 8);

  // prologue: DMA K tile 0
#pragma unroll
  for (int i = 0; i < 4; ++i) {
    int off = (i * 4 + wv) * 512;
    gload16(kfb + off + lane * 8, &kls[0][off]);
  }
  __syncthreads();

#pragma unroll 1
  for (int kt = 0; kt < NT; ++kt) {
    // ---- V A-frags (own d-half), coalesced from L2 ----
    half8 vb[8];
#pragma unroll
    for (int i = 0; i < 8; ++i)
      vb[i] = *(const half8*)(vp + i * 512);

    // ---- async DMA K(kt+1) ----
    if (kt + 1 < NT) {
      unsigned short* d = &kls[(kt + 1) & 1][wv * 512];
      gload16(sp + 0 * 2048, d + 0 * 2048);
      gload16(sp + 1 * 2048, d + 1 * 2048);
      gload16(sp + 2 * 2048, d + 2 * 2048);
      gload16(sp + 3 * 2048, d + 3 * 2048);
    }

    // ---- QK^T: full 32x32 S^T, 16 big MFMA in 2 chains ----
    const unsigned short* kb = &kls[kt & 1][0];
    f32x16 sA, sB;
#pragma unroll
    for (int i = 0; i < 16; ++i) { sA[i] = 0.f; sB[i] = 0.f; }
    __builtin_amdgcn_s_setprio(1);
#pragma unroll
    for (int ks = 0; ks < 8; ++ks) {
      half8 ka = *(const half8*)(kb + ks * 512 + lane * 8);
      sA = __builtin_amdgcn_mfma_f32_32x32x16_f16(ka, qh[ks], sA, 0, 0, 0);
    }
#pragma unroll
    for (int ks = 8; ks < 16; ++ks) {
      half8 ka = *(const half8*)(kb + ks * 512 + lane * 8);
      sB = __builtin_amdgcn_mfma_f32_32x32x16_f16(ka, qh[ks], sB, 0, 0, 0);
    }
    __builtin_amdgcn_s_setprio(0);
    float p[16];
#pragma unroll
    for (int i = 0; i < 16; ++i) p[i] = sA[i] + sB[i];

    // ---- in-lane softmax over 32 j (lane owns q=l31, 16 j; partner lane^32 has rest) ----
    float mt = p[0];
#pragma unroll
    for (int i = 1; i < 16; ++i) mt = fmaxf(mt, p[i]);
    mt = fmaxf(mt, __shfl_xor(mt, 32));
    if (__any(mt > m0r + 11.5416f)) {
      float mn = fmaxf(m0r, mt);
      float sc = ex2(m0r - mn);
      l0 *= sc;
#pragma unroll
      for (int dt = 0; dt < 4; ++dt)
#pragma unroll
        for (int i = 0; i < 16; ++i) acc[dt][i] *= sc;
      m0r = mn;
    }

    // ---- exp2 + per-lane partial sum ----
#pragma unroll
    for (int i = 0; i < 16; ++i) p[i] = ex2(p[i] - m0r);
    float s0 = ((p[0] + p[1]) + (p[2] + p[3])) + ((p[4] + p[5]) + (p[6] + p[7]));
    float s1 = ((p[8] + p[9]) + (p[10] + p[11])) + ((p[12] + p[13]) + (p[14] + p[15]));
    l0 += s0 + s1;

    // ---- P B-frags: direct pack (regs 8m+e; k-slot j-map co-permuted in vfrag) ----
    half8 pa0, pa1;
    {
      uint4v u0 = { pk2(p[0], p[1]), pk2(p[2], p[3]), pk2(p[4], p[5]), pk2(p[6], p[7]) };
      uint4v u1 = { pk2(p[8], p[9]), pk2(p[10], p[11]), pk2(p[12], p[13]), pk2(p[14], p[15]) };
      pa0 = __builtin_bit_cast(half8, u0);
      pa1 = __builtin_bit_cast(half8, u1);
    }

    // ---- PV: own d-half (4 d-tiles x 2 k-halves) ----
    __builtin_amdgcn_s_setprio(1);
#pragma unroll
    for (int dt = 0; dt < 4; ++dt) {
      acc[dt] = __builtin_amdgcn_mfma_f32_32x32x16_f16(vb[dt * 2 + 0], pa0, acc[dt], 0, 0, 0);
      acc[dt] = __builtin_amdgcn_mfma_f32_32x32x16_f16(vb[dt * 2 + 1], pa1, acc[dt], 0, 0, 0);
    }
    __builtin_amdgcn_s_setprio(0);

    vp += 8192;
    sp += 8192;
    __syncthreads();   // drains DMA for kt+1
  }

  // ---- epilogue: merge denominators (lane^32), normalize, store float4 ----
  l0 += __shfl_xor(l0, 32);
  float inv0 = 1.0f / l0;
  float* ob = out + ((size_t)b * NI + qbase + l31) * DD + h * 128 + hi * 4;
#pragma unroll
  for (int dt = 0; dt < 4; ++dt) {
#pragma unroll
    for (int rq = 0; rq < 4; ++rq) {
      float4 v;
      v.x = acc[dt][rq * 4 + 0] * inv0;
      v.y = acc[dt][rq * 4 + 1] * inv0;
      v.z = acc[dt][rq * 4 + 2] * inv0;
      v.w = acc[dt][rq * 4 + 3] * inv0;
      *(float4*)(ob + dt * 32 + rq * 8) = v;
    }
  }
}

extern "C" void kernel_launch(void* const* d_in, const int* in_sizes, int n_in,
                              void* d_out, int out_size, void* d_ws, size_t ws_size,
                              hipStream_t stream) {
  const float* x = (const float*)d_in[0];        // [16,2048,256]
  const float* att = (const float*)d_in[1];      // [16,2048,256]
  const float* W = (const float*)d_in[2];        // [256,256]
  float* out = (float*)d_out;

  const size_t NE = (size_t)BB * NA * DD;        // 8388608
  unsigned short* w0    = (unsigned short*)d_ws;
  unsigned short* kfrag = w0;
  unsigned short* vfrag = w0 + NE;
  unsigned short* qfp   = w0 + 2 * NE;
  unsigned short* wth   = w0 + 3 * NE;
  unsigned short* wtl   = w0 + 3 * NE + (size_t)DD * DD;

  prep_kernel<<<2064, 256, 0, stream>>>(att, kfrag, vfrag, W, wth, wtl);
  qgemm_kernel<<<512, 256, 0, stream>>>(x, wth, wtl, qfp);
  attn_kernel<<<512, 256, 0, stream>>>(kfrag, vfrag, qfp, out);
}